// Round 5
// baseline (252.944 us; speedup 1.0000x reference)
//
#include <hip/hip_runtime.h>
#include <hip/hip_bf16.h>
#include <stdint.h>

// ---------- types ----------
typedef __attribute__((ext_vector_type(8))) __bf16 bf16x8;
typedef __attribute__((ext_vector_type(4))) __bf16 bf16x4;
typedef __attribute__((ext_vector_type(4))) float  f32x4;
typedef __attribute__((ext_vector_type(4))) int    i32x4;

#define MFMA16(a, b, c) __builtin_amdgcn_mfma_f32_16x16x32_bf16((a), (b), (c), 0, 0, 0)

// async global->LDS, 16B per lane; LDS dest = wave-uniform base + lane*16
#define GLD16(gp, lp) __builtin_amdgcn_global_load_lds(                                   \
    (const __attribute__((address_space(1))) uint32_t*)(gp),                              \
    (__attribute__((address_space(3))) uint32_t*)(lp), 16, 0, 0)

// Problem constants
#define BB 4
#define TT 2048
#define CC 1024
#define HH 16
#define DH 64
#define GM 8192   // B*T
#define GN 1024
#define GK 1024

// ---------- fused fp32 -> bf16 conversion: x (4096 blocks) + 4 weights (512 each) ----------
__global__ __launch_bounds__(256) void cvt_all_kernel(const float* __restrict__ x,
                                                      const float* __restrict__ w0,
                                                      const float* __restrict__ w1,
                                                      const float* __restrict__ w2,
                                                      const float* __restrict__ w3,
                                                      __bf16* __restrict__ xb,
                                                      __bf16* __restrict__ wb) {
    int gb = blockIdx.x;
    const float* src;
    __bf16* dst;
    int i;
    if (gb < 4096) {                       // x plane: 8192*1024 elems
        src = x; dst = xb;
        i = gb * 256 + threadIdx.x;
    } else {                               // weights: 4 x 1024*1024
        int g = gb - 4096;
        int wz = g >> 9, lb = g & 511;
        const float* srcs[4] = {w0, w1, w2, w3};
        src = srcs[wz]; dst = wb + (size_t)wz * CC * CC;
        i = lb * 256 + threadIdx.x;
    }
    const float4* s = (const float4*)src + (size_t)i * 2;
    float4 f0 = s[0], f1 = s[1];
    bf16x8 h;
    h[0] = (__bf16)f0.x; h[1] = (__bf16)f0.y; h[2] = (__bf16)f0.z; h[3] = (__bf16)f0.w;
    h[4] = (__bf16)f1.x; h[5] = (__bf16)f1.y; h[6] = (__bf16)f1.z; h[7] = (__bf16)f1.w;
    *(bf16x8*)(dst + (size_t)i * 8) = h;
}

// ---------- bf16 transpose: V [8192][1024] -> VT [1024][8192] ----------
__global__ __launch_bounds__(256) void transpose_kernel(const __bf16* __restrict__ V,
                                                        __bf16* __restrict__ VT) {
    __shared__ __bf16 Ts[64][72];  // +8 pad
    int tid = threadIdx.x;
    int m0 = blockIdx.x * 64, c0 = blockIdx.y * 64;
#pragma unroll
    for (int r = 0; r < 2; r++) {
        int ch = r * 256 + tid;
        int mm = ch >> 3, c8 = (ch & 7) * 8;
        *(uint4*)&Ts[mm][c8] = *(const uint4*)(V + (size_t)(m0 + mm) * CC + c0 + c8);
    }
    __syncthreads();
#pragma unroll
    for (int r = 0; r < 2; r++) {
        int ch = r * 256 + tid;
        int cc = ch >> 3, m8 = (ch & 7) * 8;
        bf16x8 v;
#pragma unroll
        for (int e = 0; e < 8; e++) v[e] = Ts[m8 + e][cc];
        *(bf16x8*)(VT + (size_t)(c0 + cc) * GM + m0 + m8) = v;
    }
}

// ---------- 4-phase NT GEMM: C[m,n] = sum_k A[m,k] * B[n,k] ----------
// (round-4-verified, byte-for-byte)
__global__ __launch_bounds__(512, 2) void gemm8(const __bf16* __restrict__ A,
                                                const __bf16* __restrict__ Bmat,
                                                __bf16* __restrict__ Cbf,
                                                float* __restrict__ Cf) {
    __shared__ __align__(16) char lds[98304];
    char* ldsA = lds;           // 4 x 16384
    char* ldsB = lds + 65536;   // 4 x 8192

    int id = blockIdx.x;
    int xcd = id & 7, slot = id >> 3;          // round-robin dispatch: id&7 = XCD
    int mb = xcd * 4 + (slot & 3);             // XCD m-stripe: A 2MB stays L2-hot
    int nb = slot >> 2;
    int m0 = mb * 256, n0 = nb * 128;

    int tid  = threadIdx.x;
    int lane = tid & 63, w = tid >> 6;
    int wm = w >> 1, wn = w & 1;               // 4 M-warps x 2 N-warps
    int l15 = lane & 15, q8 = lane >> 4;
    int x7  = l15 & 7;

    // staging source (pre-swizzled): thread covers row=tid>>3,
    // stored chunk tid&7 holds logical chunk (tid&7)^(row&7)
    int arow = tid >> 3;
    int lc   = (tid & 7) ^ (arow & 7);
    const __bf16* Abase = A    + (size_t)(m0 + arow) * GK + lc * 8;
    const __bf16* Bbase = Bmat + (size_t)(n0 + arow) * GK + lc * 8;
    int wbase = (tid & ~63) * 16;

    // swizzled ds_read offsets: chunk c=kk*4+q8 stored at c^(row&7); row&7==l15&7
    int cb0 = ((q8)     ^ x7) * 16;
    int cb1 = ((q8 + 4) ^ x7) * 16;
    int arb0 = (wm * 32 + l15) * 128;
    int arb1 = (wm * 32 + 16 + l15) * 128;
    int brb0 = (wn * 32 + l15) * 128;
    int brb1 = (wn * 32 + 16 + l15) * 128;

    f32x4 zero = {0.f, 0.f, 0.f, 0.f};
    f32x4 acc[4][4];
#pragma unroll
    for (int i = 0; i < 4; i++)
#pragma unroll
        for (int j = 0; j < 4; j++) acc[i][j] = zero;

    bf16x8 areg[2][2];   // current m-half frags [mloc][kk]
    bf16x8 breg[4][2];   // all 4 n-frags [nt][kk]

#define STAGE_A(T_, H_) do {                                                              \
        const __bf16* _g = Abase + (size_t)((H_) * 128) * GK + (((T_) & 15) * 64);        \
        char* _d = ldsA + ((((T_) & 1) * 2 + (H_)) * 16384) + wbase;                      \
        GLD16(_g, _d);                                                                    \
        GLD16(_g + (size_t)64 * GK, _d + 8192);                                           \
    } while (0)
#define STAGE_B(T_, H_) do {                                                              \
        const __bf16* _g = Bbase + (size_t)((H_) * 64) * GK + (((T_) & 15) * 64);         \
        GLD16(_g, ldsB + ((((T_) & 1) * 2 + (H_)) * 8192) + wbase);                       \
    } while (0)
#define LD_A(BK_, H_) do {                                                                \
        char* _p = ldsA + (((BK_) * 2 + (H_)) * 16384);                                   \
        areg[0][0] = *(const bf16x8*)(_p + arb0 + cb0);                                   \
        areg[0][1] = *(const bf16x8*)(_p + arb0 + cb1);                                   \
        areg[1][0] = *(const bf16x8*)(_p + arb1 + cb0);                                   \
        areg[1][1] = *(const bf16x8*)(_p + arb1 + cb1);                                   \
    } while (0)
#define LD_B(BK_, H_) do {                                                                \
        char* _p = ldsB + (((BK_) * 2 + (H_)) * 8192);                                    \
        breg[(H_) * 2 + 0][0] = *(const bf16x8*)(_p + brb0 + cb0);                        \
        breg[(H_) * 2 + 0][1] = *(const bf16x8*)(_p + brb0 + cb1);                        \
        breg[(H_) * 2 + 1][0] = *(const bf16x8*)(_p + brb1 + cb0);                        \
        breg[(H_) * 2 + 1][1] = *(const bf16x8*)(_p + brb1 + cb1);                        \
    } while (0)
// kk0 for 4 independent (m,n) pairs, then kk1: MFMA dep-chain distance 4
#define QMFMA(MH_, N0_, N1_) do {                                                         \
        acc[(MH_)*2+0][N0_] = MFMA16(areg[0][0], breg[N0_][0], acc[(MH_)*2+0][N0_]);      \
        acc[(MH_)*2+0][N1_] = MFMA16(areg[0][0], breg[N1_][0], acc[(MH_)*2+0][N1_]);      \
        acc[(MH_)*2+1][N0_] = MFMA16(areg[1][0], breg[N0_][0], acc[(MH_)*2+1][N0_]);      \
        acc[(MH_)*2+1][N1_] = MFMA16(areg[1][0], breg[N1_][0], acc[(MH_)*2+1][N1_]);      \
        acc[(MH_)*2+0][N0_] = MFMA16(areg[0][1], breg[N0_][1], acc[(MH_)*2+0][N0_]);      \
        acc[(MH_)*2+0][N1_] = MFMA16(areg[0][1], breg[N1_][1], acc[(MH_)*2+0][N1_]);      \
        acc[(MH_)*2+1][N0_] = MFMA16(areg[1][1], breg[N0_][1], acc[(MH_)*2+1][N0_]);      \
        acc[(MH_)*2+1][N1_] = MFMA16(areg[1][1], breg[N1_][1], acc[(MH_)*2+1][N1_]);      \
    } while (0)
#define BAR   __builtin_amdgcn_s_barrier()
#define PRIO1 __builtin_amdgcn_s_setprio(1)
#define PRIO0 __builtin_amdgcn_s_setprio(0)
#define VM6   asm volatile("s_waitcnt vmcnt(6)" ::: "memory")
#define VM4   asm volatile("s_waitcnt vmcnt(4)" ::: "memory")

    // prologue: tile0 full (6), tile1 partial B+A-h0 (4); VM4 drains tile0
    STAGE_B(0, 0); STAGE_B(0, 1); STAGE_A(0, 0); STAGE_A(0, 1);
    STAGE_B(1, 0); STAGE_B(1, 1); STAGE_A(1, 0);
    VM4;
    BAR;

    for (int i = 0; i < 8; i++) {
        int t = 2 * i;
        // P0
        LD_A(0, 0); LD_B(0, 0); LD_B(0, 1);
        STAGE_A(t + 1, 1);
        BAR; PRIO1; QMFMA(0, 0, 1); QMFMA(0, 2, 3); PRIO0; BAR;
        // P1
        LD_A(0, 1);
        STAGE_B(t + 2, 0); STAGE_B(t + 2, 1); STAGE_A(t + 2, 0);
        BAR; PRIO1; QMFMA(1, 0, 1); QMFMA(1, 2, 3); PRIO0; VM6; BAR;
        // P2
        LD_A(1, 0); LD_B(1, 0); LD_B(1, 1);
        STAGE_A(t + 2, 1);
        BAR; PRIO1; QMFMA(0, 0, 1); QMFMA(0, 2, 3); PRIO0; VM6; BAR;
        // P3
        LD_A(1, 1);
        STAGE_B(t + 3, 0); STAGE_B(t + 3, 1); STAGE_A(t + 3, 0);
        BAR; PRIO1; QMFMA(1, 0, 1); QMFMA(1, 2, 3); PRIO0; VM4; BAR;
    }

    // drain wrapped prefetches before LDS goes out of scope
    asm volatile("s_waitcnt vmcnt(0)" ::: "memory");

    // epilogue: C/D layout col = lane&15 (n), row = q8*4 + reg (m)
    int zc  = n0 >> 10;          // QKV plane (0 for out-proj)
    int ncb = n0 & 1023;
#pragma unroll
    for (int mt = 0; mt < 4; mt++) {
        int mrow = m0 + (mt >> 1) * 128 + wm * 32 + (mt & 1) * 16 + q8 * 4;
#pragma unroll
        for (int nt = 0; nt < 4; nt++) {
            int ncol = ncb + (nt >> 1) * 64 + wn * 32 + (nt & 1) * 16 + l15;
            f32x4 v = acc[mt][nt];
            if (Cf) {
                float* p = Cf + (size_t)mrow * GN + ncol;
                p[0] = v.x; p[GN] = v.y; p[2 * GN] = v.z; p[3 * GN] = v.w;
            } else {
                __bf16* p = Cbf + (size_t)zc * ((size_t)GM * GN) + (size_t)mrow * GN + ncol;
                p[0] = (__bf16)v.x; p[GN] = (__bf16)v.y;
                p[2 * GN] = (__bf16)v.z; p[3 * GN] = (__bf16)v.w;
            }
        }
    }
#undef STAGE_A
#undef STAGE_B
#undef LD_A
#undef LD_B
#undef QMFMA
#undef BAR
#undef PRIO1
#undef PRIO0
#undef VM6
#undef VM4
}

// ---------- flash attention, causal, S^T formulation, STATIC-MAX softmax ----------
// Phase C transpose is now fully in-register, built ONLY from semantically-
// certain primitives (no cvt_pk asm, no permlane asm):
//   Source: lane(l15,q8), reg r of st-block holds P[s=st*16+q8*4+r][q=l15].
//   Target B-frag bp[qf][pr]: lane(l15,g) dword d = bf16 pair
//     (s0=pr*32+g*8+2d, s0+1) of column l15, i.e. value (d&1?hiPack:loPack)
//     [st=2pr+(g>>1)] fetched from source lane (2(g&1)+(d>>1))*16+l15.
//   Build: per st-pair, form a'=[S0.lo|S1.lo], b'=[S0.hi|S1.hi] via
//   shfl_xor(32)+sel(bit5); then d0=sel(bit4, swz0F(b'), a'),
//   d2=sel(bit4, b', swzOr16(a')) (same for hi-pack regs -> d1/d3).
//   Lane-algebra spot-checked at lanes 5,21,37,53 for all dword classes.
__global__ __launch_bounds__(256) void attn_kernel(const __bf16* __restrict__ Q,
                                                   const __bf16* __restrict__ K,
                                                   const __bf16* __restrict__ VT,
                                                   __bf16* __restrict__ Y) {
    __shared__ __bf16 Ks[2][64 * 64];  // [s][d], chunk-swizzled, dbuf
    __shared__ __bf16 Vs[2][64 * 64];  // [d][s], chunk-swizzled, dbuf

    int tid  = threadIdx.x;
    int lane = tid & 63, w = tid >> 6;
    int l15 = lane & 15, q8 = lane >> 4;
    int y  = blockIdx.y, y0 = y & 3, kk = y >> 2;
    int qt = (kk & 1) ? (2 * y0 + (kk >> 1)) : (15 - (kk >> 1) - 2 * y0);
    int bh = blockIdx.x, b = bh >> 4, h = bh & 15;
    size_t rowb = (size_t)b * TT;
    const float SC = 0.125f * 1.44269504f;   // scale * log2(e), folded into Q
    const float M2 = 12.0f * 1.44269504f;    // static max (log2 domain)
    int ql = w * 16 + l15;             // q offset within strip
    int x7 = l15 & 7;                  // xor-swizzle key (row & 7)
    bool hi4 = (lane & 16) != 0;
    bool hi5 = (lane & 32) != 0;

    // Q B-frags (n = q, k = d), pre-scaled by SC
    bf16x8 qfr[2][2];
#pragma unroll
    for (int qf = 0; qf < 2; qf++) {
        int q = qt * 128 + qf * 64 + w * 16 + l15;
        const __bf16* qp = Q + (rowb + q) * CC + h * DH + q8 * 8;
        bf16x8 r0 = *(const bf16x8*)qp;
        bf16x8 r1 = *(const bf16x8*)(qp + 32);
#pragma unroll
        for (int e = 0; e < 8; e++) {
            r0[e] = (__bf16)((float)r0[e] * SC);
            r1[e] = (__bf16)((float)r1[e] * SC);
        }
        qfr[qf][0] = r0; qfr[qf][1] = r1;
    }

    f32x4 zero = {0.f, 0.f, 0.f, 0.f};
    f32x4 acc[2][5];
#pragma unroll
    for (int qf = 0; qf < 2; qf++)
#pragma unroll
        for (int t5 = 0; t5 < 5; t5++) acc[qf][t5] = zero;

    // ones A-frag: row 0 of the l-tile accumulates l = sum_s P^T[s][q]
    bf16x8 ones;
#pragma unroll
    for (int e = 0; e < 8; e++) ones[e] = (l15 == 0) ? (__bf16)1.0f : (__bf16)0.0f;

    // staging: chunk c -> (row c>>3, swizzled col-chunk c&7)
    int c0 = tid, c1 = tid + 256;
    int s0 = c0 >> 3, d80 = ((c0 & 7) ^ (s0 & 7)) * 8;
    int s1 = c1 >> 3, d81 = ((c1 & 7) ^ (s1 & 7)) * 8;
    const __bf16* Kg0 = K + (rowb + s0) * CC + h * DH + d80;
    const __bf16* Kg1 = K + (rowb + s1) * CC + h * DH + d81;
    const __bf16* Vg0 = VT + (size_t)(h * DH + s0) * GM + rowb + d80;
    const __bf16* Vg1 = VT + (size_t)(h * DH + s1) * GM + rowb + d81;
    char* KsB = (char*)Ks; char* VsB = (char*)Vs;
    int wbase = (tid & ~63) * 16;

    // prologue: stage key-tile 0 into buffer 0
    GLD16(Kg0, KsB + wbase);
    GLD16(Kg1, KsB + 4096 + wbase);
    GLD16(Vg0, VsB + wbase);
    GLD16(Vg1, VsB + 4096 + wbase);

    int jmax = 2 * qt + 1;
    for (int j = 0; j <= jmax; j++) {
        __syncthreads();   // drains GLD(j) + all waves done reading other buf
        if (j < jmax) {    // prefetch tile j+1 into the other buffer
            int bo = ((j + 1) & 1) * 8192;
            GLD16(Kg0 + (size_t)(j + 1) * 64 * CC, KsB + bo + wbase);
            GLD16(Kg1 + (size_t)(j + 1) * 64 * CC, KsB + bo + 4096 + wbase);
            GLD16(Vg0 + (j + 1) * 64, VsB + bo + wbase);
            GLD16(Vg1 + (j + 1) * 64, VsB + bo + 4096 + wbase);
        }
        const __bf16* Kc = &Ks[j & 1][0];
        const __bf16* Vc = &Vs[j & 1][0];
        bool do0 = (j != jmax);          // strip 0 fully masked on the last k-tile

        // phase A: S^T = K.Q^T (pre-scaled)
        f32x4 s2[2][4];
#pragma unroll
        for (int st = 0; st < 4; st++) {
            bf16x8 k0f = *(const bf16x8*)(Kc + (st * 16 + l15) * 64 + ((q8 ^ x7) * 8));
            bf16x8 k1f = *(const bf16x8*)(Kc + (st * 16 + l15) * 64 + (((q8 + 4) ^ x7) * 8));
            f32x4 t1 = zero;
            t1 = MFMA16(k0f, qfr[1][0], t1);
            t1 = MFMA16(k1f, qfr[1][1], t1);
            s2[1][st] = t1;
            if (do0) {
                f32x4 t0 = zero;
                t0 = MFMA16(k0f, qfr[0][0], t0);
                t0 = MFMA16(k1f, qfr[0][1], t0);
                s2[0][st] = t0;
            }
        }

        // phase B: causal mask on the diagonal iter only (wave-uniform branch)
#pragma unroll
        for (int qf = 0; qf < 2; qf++) {
            if (qf == 0 && !do0) continue;
            if (j == 2 * qt + qf) {
#pragma unroll
                for (int st = 0; st < 4; st++) {
                    f32x4 t = s2[qf][st];
                    int sb = st * 16 + q8 * 4;
                    t.x = (sb + 0 > ql) ? -1e30f : t.x;
                    t.y = (sb + 1 > ql) ? -1e30f : t.y;
                    t.z = (sb + 2 > ql) ? -1e30f : t.z;
                    t.w = (sb + 3 > ql) ? -1e30f : t.w;
                    s2[qf][st] = t;
                }
            }
        }

        // phase C: P = exp2(s - M2); in-register C->B-frag transpose (no LDS)
        bf16x8 bp[2][2];
#pragma unroll
        for (int qf = 0; qf < 2; qf++) {
            if (qf == 0 && !do0) continue;
            uint32_t pkl[4], pkh[4];
#pragma unroll
            for (int st = 0; st < 4; st++) {
                uint32_t b0 = (uint32_t)__builtin_bit_cast(uint16_t,
                    (__bf16)__builtin_amdgcn_exp2f(s2[qf][st].x - M2));
                uint32_t b1 = (uint32_t)__builtin_bit_cast(uint16_t,
                    (__bf16)__builtin_amdgcn_exp2f(s2[qf][st].y - M2));
                uint32_t b2 = (uint32_t)__builtin_bit_cast(uint16_t,
                    (__bf16)__builtin_amdgcn_exp2f(s2[qf][st].z - M2));
                uint32_t b3 = (uint32_t)__builtin_bit_cast(uint16_t,
                    (__bf16)__builtin_amdgcn_exp2f(s2[qf][st].w - M2));
                pkl[st] = b0 | (b1 << 16);   // (r0, r1) -> s even pair
                pkh[st] = b2 | (b3 << 16);   // (r2, r3)
            }
#pragma unroll
            for (int pr = 0; pr < 2; pr++) {
                int A0 = (int)pkl[2 * pr],     B0 = (int)pkh[2 * pr];
                int A1 = (int)pkl[2 * pr + 1], B1 = (int)pkh[2 * pr + 1];
                int A0x = __shfl_xor(A0, 32), A1x = __shfl_xor(A1, 32);
                int B0x = __shfl_xor(B0, 32), B1x = __shfl_xor(B1, 32);
                int au = hi5 ? A1x : A0;    // a' = [A0.lo | A1.lo]
                int bu = hi5 ? A1  : A0x;   // b' = [A0.hi | A1.hi]
                int av = hi5 ? B1x : B0;
                int bv = hi5 ? B1  : B0x;
                int sbu = __builtin_amdgcn_ds_swizzle(bu, 0x000F);  // src=lane&15 (in 32-grp)
                int sbv = __builtin_amdgcn_ds_swizzle(bv, 0x000F);
                int sau = __builtin_amdgcn_ds_swizzle(au, 0x020F);  // src=(lane&15)|16
                int sav = __builtin_amdgcn_ds_swizzle(av, 0x020F);
                i32x4 wv;
                wv.x = hi4 ? sbu : au;
                wv.y = hi4 ? sbv : av;
                wv.z = hi4 ? bu  : sau;
                wv.w = hi4 ? bv  : sav;
                bp[qf][pr] = __builtin_bit_cast(bf16x8, wv);
            }
        }

        // phase D: O^T += V^T P^T ; l-row via ones-MFMA
#pragma unroll
        for (int dt = 0; dt < 4; dt++) {
            bf16x8 v0 = *(const bf16x8*)(Vc + (dt * 16 + l15) * 64 + ((q8 ^ x7) * 8));
            bf16x8 v1 = *(const bf16x8*)(Vc + (dt * 16 + l15) * 64 + (((q8 + 4) ^ x7) * 8));
            acc[1][dt] = MFMA16(v0, bp[1][0], acc[1][dt]);
            acc[1][dt] = MFMA16(v1, bp[1][1], acc[1][dt]);
            if (do0) {
                acc[0][dt] = MFMA16(v0, bp[0][0], acc[0][dt]);
                acc[0][dt] = MFMA16(v1, bp[0][1], acc[0][dt]);
            }
        }
        acc[1][4] = MFMA16(ones, bp[1][0], acc[1][4]);
        acc[1][4] = MFMA16(ones, bp[1][1], acc[1][4]);
        if (do0) {
            acc[0][4] = MFMA16(ones, bp[0][0], acc[0][4]);
            acc[0][4] = MFMA16(ones, bp[0][1], acc[0][4]);
        }
    }

    // epilogue: O^T C-layout col=l15=q, row=q8*4+r=d; l in acc[qf][4].x at lane l15
#pragma unroll
    for (int qf = 0; qf < 2; qf++) {
        float lsum = __shfl(acc[qf][4].x, l15);
        float ri = 1.0f / lsum;
        int q = qt * 128 + qf * 64 + w * 16 + l15;
        __bf16* yp = Y + (rowb + q) * CC + h * DH + q8 * 4;
#pragma unroll
        for (int dt = 0; dt < 4; dt++) {
            bf16x4 o;
            o[0] = (__bf16)(acc[qf][dt].x * ri);
            o[1] = (__bf16)(acc[qf][dt].y * ri);
            o[2] = (__bf16)(acc[qf][dt].z * ri);
            o[3] = (__bf16)(acc[qf][dt].w * ri);
            *(bf16x4*)(yp + dt * 16) = o;
        }
    }
}

// ---------- launch ----------
extern "C" void kernel_launch(void* const* d_in, const int* in_sizes, int n_in,
                              void* d_out, int out_size, void* d_ws, size_t ws_size,
                              hipStream_t stream) {
    const float* x  = (const float*)d_in[0];
    const float* wq = (const float*)d_in[1];
    const float* wk = (const float*)d_in[2];
    const float* wv = (const float*)d_in[3];
    const float* wo = (const float*)d_in[4];
    float* out = (float*)d_out;

    char* ws = (char*)d_ws;
    __bf16* xb  = (__bf16*)ws;                              // [0,16M): xb, then VT after QKV GEMM
    __bf16* wb  = (__bf16*)(ws + (size_t)16777216);         // [16M,24M): 4 weights bf16
    __bf16* qkv = (__bf16*)(ws + (size_t)25165824);         // [24M,72M): Q,K,V planes
    __bf16* yb  = (__bf16*)(ws + (size_t)75497472);         // [72M,88M): attn out bf16

    // fused conversion: x (4096 blocks) + 4 weight planes (4*512 blocks)
    cvt_all_kernel<<<dim3(4096 + 4 * 512), 256, 0, stream>>>(x, wq, wk, wv, wo, xb, wb);
    // fused QKV GEMM: M=8192, N=3072 (wq|wk|wv contiguous in wb), K=1024.
    // 768 blocks = 8 XCD x 96 = exactly 3 rounds at 1 block/CU.
    gemm8<<<dim3(768), 512, 0, stream>>>(xb, wb, qkv, nullptr);
    // V plane -> VT [1024][8192]; xb region is dead now, reuse it
    transpose_kernel<<<dim3(GM / 64, GN / 64), 256, 0, stream>>>(
        qkv + (size_t)2 * GM * GN, xb);
    // grid: x = bh (64), y = balanced qt permutation (16)
    attn_kernel<<<dim3(BB * HH, 16), 256, 0, stream>>>(
        qkv, qkv + (size_t)GM * GN, xb, yb);
    // output projection: 256 blocks = exactly 1 round, fp32 out
    gemm8<<<dim3(256), 512, 0, stream>>>(yb, wb + (size_t)3 * CC * CC, nullptr, out);
}

// Round 6
// 230.321 us; speedup vs baseline: 1.0982x; 1.0982x over previous
//
#include <hip/hip_runtime.h>
#include <hip/hip_bf16.h>
#include <stdint.h>

// ---------- types ----------
typedef __attribute__((ext_vector_type(8))) __bf16 bf16x8;
typedef __attribute__((ext_vector_type(4))) __bf16 bf16x4;
typedef __attribute__((ext_vector_type(4))) float  f32x4;

#define MFMA16(a, b, c) __builtin_amdgcn_mfma_f32_16x16x32_bf16((a), (b), (c), 0, 0, 0)

// async global->LDS, 16B per lane; LDS dest = wave-uniform base + lane*16
#define GLD16(gp, lp) __builtin_amdgcn_global_load_lds(                                   \
    (const __attribute__((address_space(1))) uint32_t*)(gp),                              \
    (__attribute__((address_space(3))) uint32_t*)(lp), 16, 0, 0)

// Problem constants
#define BB 4
#define TT 2048
#define CC 1024
#define HH 16
#define DH 64
#define GM 8192   // B*T
#define GN 1024
#define GK 1024

// ---------- fused fp32 -> bf16 conversion: x (4096 blocks) + 4 weights (512 each) ----------
__global__ __launch_bounds__(256) void cvt_all_kernel(const float* __restrict__ x,
                                                      const float* __restrict__ w0,
                                                      const float* __restrict__ w1,
                                                      const float* __restrict__ w2,
                                                      const float* __restrict__ w3,
                                                      __bf16* __restrict__ xb,
                                                      __bf16* __restrict__ wb) {
    int gb = blockIdx.x;
    const float* src;
    __bf16* dst;
    int i;
    if (gb < 4096) {                       // x plane: 8192*1024 elems
        src = x; dst = xb;
        i = gb * 256 + threadIdx.x;
    } else {                               // weights: 4 x 1024*1024
        int g = gb - 4096;
        int wz = g >> 9, lb = g & 511;
        const float* srcs[4] = {w0, w1, w2, w3};
        src = srcs[wz]; dst = wb + (size_t)wz * CC * CC;
        i = lb * 256 + threadIdx.x;
    }
    const float4* s = (const float4*)src + (size_t)i * 2;
    float4 f0 = s[0], f1 = s[1];
    bf16x8 h;
    h[0] = (__bf16)f0.x; h[1] = (__bf16)f0.y; h[2] = (__bf16)f0.z; h[3] = (__bf16)f0.w;
    h[4] = (__bf16)f1.x; h[5] = (__bf16)f1.y; h[6] = (__bf16)f1.z; h[7] = (__bf16)f1.w;
    *(bf16x8*)(dst + (size_t)i * 8) = h;
}

// ---------- 4-phase NT GEMM: C[m,n] = sum_k A[m,k] * B[n,k] ----------
// Main loop byte-identical to round-4-verified version. Epilogue change only:
// the V plane (zc==2, QKV call) is written TRANSPOSED (VT[n][m]) into the
// qkv plane-2 slot -- the C/D frag's 4 values are m-consecutive at fixed n,
// i.e. contiguous in VT -> one bf16x4 store. Kills the transpose kernel.
__global__ __launch_bounds__(512, 2) void gemm8(const __bf16* __restrict__ A,
                                                const __bf16* __restrict__ Bmat,
                                                __bf16* __restrict__ Cbf,
                                                float* __restrict__ Cf) {
    __shared__ __align__(16) char lds[98304];
    char* ldsA = lds;           // 4 x 16384
    char* ldsB = lds + 65536;   // 4 x 8192

    int id = blockIdx.x;
    int xcd = id & 7, slot = id >> 3;          // round-robin dispatch: id&7 = XCD
    int mb = xcd * 4 + (slot & 3);             // XCD m-stripe: A 2MB stays L2-hot
    int nb = slot >> 2;
    int m0 = mb * 256, n0 = nb * 128;

    int tid  = threadIdx.x;
    int lane = tid & 63, w = tid >> 6;
    int wm = w >> 1, wn = w & 1;               // 4 M-warps x 2 N-warps
    int l15 = lane & 15, q8 = lane >> 4;
    int x7  = l15 & 7;

    // staging source (pre-swizzled): thread covers row=tid>>3,
    // stored chunk tid&7 holds logical chunk (tid&7)^(row&7)
    int arow = tid >> 3;
    int lc   = (tid & 7) ^ (arow & 7);
    const __bf16* Abase = A    + (size_t)(m0 + arow) * GK + lc * 8;
    const __bf16* Bbase = Bmat + (size_t)(n0 + arow) * GK + lc * 8;
    int wbase = (tid & ~63) * 16;

    // swizzled ds_read offsets: chunk c=kk*4+q8 stored at c^(row&7); row&7==l15&7
    int cb0 = ((q8)     ^ x7) * 16;
    int cb1 = ((q8 + 4) ^ x7) * 16;
    int arb0 = (wm * 32 + l15) * 128;
    int arb1 = (wm * 32 + 16 + l15) * 128;
    int brb0 = (wn * 32 + l15) * 128;
    int brb1 = (wn * 32 + 16 + l15) * 128;

    f32x4 zero = {0.f, 0.f, 0.f, 0.f};
    f32x4 acc[4][4];
#pragma unroll
    for (int i = 0; i < 4; i++)
#pragma unroll
        for (int j = 0; j < 4; j++) acc[i][j] = zero;

    bf16x8 areg[2][2];   // current m-half frags [mloc][kk]
    bf16x8 breg[4][2];   // all 4 n-frags [nt][kk]

#define STAGE_A(T_, H_) do {                                                              \
        const __bf16* _g = Abase + (size_t)((H_) * 128) * GK + (((T_) & 15) * 64);        \
        char* _d = ldsA + ((((T_) & 1) * 2 + (H_)) * 16384) + wbase;                      \
        GLD16(_g, _d);                                                                    \
        GLD16(_g + (size_t)64 * GK, _d + 8192);                                           \
    } while (0)
#define STAGE_B(T_, H_) do {                                                              \
        const __bf16* _g = Bbase + (size_t)((H_) * 64) * GK + (((T_) & 15) * 64);         \
        GLD16(_g, ldsB + ((((T_) & 1) * 2 + (H_)) * 8192) + wbase);                       \
    } while (0)
#define LD_A(BK_, H_) do {                                                                \
        char* _p = ldsA + (((BK_) * 2 + (H_)) * 16384);                                   \
        areg[0][0] = *(const bf16x8*)(_p + arb0 + cb0);                                   \
        areg[0][1] = *(const bf16x8*)(_p + arb0 + cb1);                                   \
        areg[1][0] = *(const bf16x8*)(_p + arb1 + cb0);                                   \
        areg[1][1] = *(const bf16x8*)(_p + arb1 + cb1);                                   \
    } while (0)
#define LD_B(BK_, H_) do {                                                                \
        char* _p = ldsB + (((BK_) * 2 + (H_)) * 8192);                                    \
        breg[(H_) * 2 + 0][0] = *(const bf16x8*)(_p + brb0 + cb0);                        \
        breg[(H_) * 2 + 0][1] = *(const bf16x8*)(_p + brb0 + cb1);                        \
        breg[(H_) * 2 + 1][0] = *(const bf16x8*)(_p + brb1 + cb0);                        \
        breg[(H_) * 2 + 1][1] = *(const bf16x8*)(_p + brb1 + cb1);                        \
    } while (0)
// kk0 for 4 independent (m,n) pairs, then kk1: MFMA dep-chain distance 4
#define QMFMA(MH_, N0_, N1_) do {                                                         \
        acc[(MH_)*2+0][N0_] = MFMA16(areg[0][0], breg[N0_][0], acc[(MH_)*2+0][N0_]);      \
        acc[(MH_)*2+0][N1_] = MFMA16(areg[0][0], breg[N1_][0], acc[(MH_)*2+0][N1_]);      \
        acc[(MH_)*2+1][N0_] = MFMA16(areg[1][0], breg[N0_][0], acc[(MH_)*2+1][N0_]);      \
        acc[(MH_)*2+1][N1_] = MFMA16(areg[1][0], breg[N1_][0], acc[(MH_)*2+1][N1_]);      \
        acc[(MH_)*2+0][N0_] = MFMA16(areg[0][1], breg[N0_][1], acc[(MH_)*2+0][N0_]);      \
        acc[(MH_)*2+0][N1_] = MFMA16(areg[0][1], breg[N1_][1], acc[(MH_)*2+0][N1_]);      \
        acc[(MH_)*2+1][N0_] = MFMA16(areg[1][1], breg[N0_][1], acc[(MH_)*2+1][N0_]);      \
        acc[(MH_)*2+1][N1_] = MFMA16(areg[1][1], breg[N1_][1], acc[(MH_)*2+1][N1_]);      \
    } while (0)
#define BAR   __builtin_amdgcn_s_barrier()
#define PRIO1 __builtin_amdgcn_s_setprio(1)
#define PRIO0 __builtin_amdgcn_s_setprio(0)
#define VM6   asm volatile("s_waitcnt vmcnt(6)" ::: "memory")
#define VM4   asm volatile("s_waitcnt vmcnt(4)" ::: "memory")

    // prologue: tile0 full (6), tile1 partial B+A-h0 (4); VM4 drains tile0
    STAGE_B(0, 0); STAGE_B(0, 1); STAGE_A(0, 0); STAGE_A(0, 1);
    STAGE_B(1, 0); STAGE_B(1, 1); STAGE_A(1, 0);
    VM4;
    BAR;

    for (int i = 0; i < 8; i++) {
        int t = 2 * i;
        // P0
        LD_A(0, 0); LD_B(0, 0); LD_B(0, 1);
        STAGE_A(t + 1, 1);
        BAR; PRIO1; QMFMA(0, 0, 1); QMFMA(0, 2, 3); PRIO0; BAR;
        // P1
        LD_A(0, 1);
        STAGE_B(t + 2, 0); STAGE_B(t + 2, 1); STAGE_A(t + 2, 0);
        BAR; PRIO1; QMFMA(1, 0, 1); QMFMA(1, 2, 3); PRIO0; VM6; BAR;
        // P2
        LD_A(1, 0); LD_B(1, 0); LD_B(1, 1);
        STAGE_A(t + 2, 1);
        BAR; PRIO1; QMFMA(0, 0, 1); QMFMA(0, 2, 3); PRIO0; VM6; BAR;
        // P3
        LD_A(1, 1);
        STAGE_B(t + 3, 0); STAGE_B(t + 3, 1); STAGE_A(t + 3, 0);
        BAR; PRIO1; QMFMA(1, 0, 1); QMFMA(1, 2, 3); PRIO0; VM4; BAR;
    }

    // drain wrapped prefetches before LDS goes out of scope
    asm volatile("s_waitcnt vmcnt(0)" ::: "memory");

    // epilogue: C/D layout col = lane&15 (n), row = q8*4 + reg (m)
    int zc  = n0 >> 10;          // QKV plane (0 for out-proj)
    int ncb = n0 & 1023;
#pragma unroll
    for (int mt = 0; mt < 4; mt++) {
        int mrow = m0 + (mt >> 1) * 128 + wm * 32 + (mt & 1) * 16 + q8 * 4;
#pragma unroll
        for (int nt = 0; nt < 4; nt++) {
            int ncol = ncb + (nt >> 1) * 64 + wn * 32 + (nt & 1) * 16 + l15;
            f32x4 v = acc[mt][nt];
            if (Cf) {
                float* p = Cf + (size_t)mrow * GN + ncol;
                p[0] = v.x; p[GN] = v.y; p[2 * GN] = v.z; p[3 * GN] = v.w;
            } else if (zc == 2) {
                // V plane: store transposed (VT[n][m], 4 m-consecutive = contiguous)
                __bf16* p = Cbf + (size_t)2 * ((size_t)GM * GN) + (size_t)ncol * GM + mrow;
                bf16x4 o;
                o[0] = (__bf16)v.x; o[1] = (__bf16)v.y;
                o[2] = (__bf16)v.z; o[3] = (__bf16)v.w;
                *(bf16x4*)p = o;
            } else {
                __bf16* p = Cbf + (size_t)zc * ((size_t)GM * GN) + (size_t)mrow * GN + ncol;
                p[0] = (__bf16)v.x; p[GN] = (__bf16)v.y;
                p[2 * GN] = (__bf16)v.z; p[3 * GN] = (__bf16)v.w;
            }
        }
    }
#undef STAGE_A
#undef STAGE_B
#undef LD_A
#undef LD_B
#undef QMFMA
#undef BAR
#undef PRIO1
#undef PRIO0
#undef VM6
#undef VM4
}

// ---------- flash attention, causal, S^T formulation, STATIC-MAX softmax ----------
// (round-4-verified version, byte-for-byte: Ps LDS round-trip + static max M2)
__global__ __launch_bounds__(256) void attn_kernel(const __bf16* __restrict__ Q,
                                                   const __bf16* __restrict__ K,
                                                   const __bf16* __restrict__ VT,
                                                   __bf16* __restrict__ Y) {
    __shared__ __bf16 Ks[2][64 * 64];  // [s][d], chunk-swizzled, dbuf
    __shared__ __bf16 Vs[2][64 * 64];  // [d][s], chunk-swizzled, dbuf
    __shared__ __bf16 Ps[4][16 * 64];  // per-wave P [q][s], chunk-swizzled

    int tid  = threadIdx.x;
    int lane = tid & 63, w = tid >> 6;
    int l15 = lane & 15, q8 = lane >> 4;
    int y  = blockIdx.y, y0 = y & 3, kk = y >> 2;
    int qt = (kk & 1) ? (2 * y0 + (kk >> 1)) : (15 - (kk >> 1) - 2 * y0);
    int bh = blockIdx.x, b = bh >> 4, h = bh & 15;
    size_t rowb = (size_t)b * TT;
    const float SC = 0.125f * 1.44269504f;   // scale * log2(e), folded into Q
    const float M2 = 12.0f * 1.44269504f;    // static max (log2 domain)
    int ql = w * 16 + l15;             // q offset within strip
    int x7 = l15 & 7;                  // xor-swizzle key (row & 7)

    // Q B-frags (n = q, k = d), pre-scaled by SC
    bf16x8 qfr[2][2];
#pragma unroll
    for (int qf = 0; qf < 2; qf++) {
        int q = qt * 128 + qf * 64 + w * 16 + l15;
        const __bf16* qp = Q + (rowb + q) * CC + h * DH + q8 * 8;
        bf16x8 r0 = *(const bf16x8*)qp;
        bf16x8 r1 = *(const bf16x8*)(qp + 32);
#pragma unroll
        for (int e = 0; e < 8; e++) {
            r0[e] = (__bf16)((float)r0[e] * SC);
            r1[e] = (__bf16)((float)r1[e] * SC);
        }
        qfr[qf][0] = r0; qfr[qf][1] = r1;
    }

    f32x4 zero = {0.f, 0.f, 0.f, 0.f};
    f32x4 acc[2][5];
#pragma unroll
    for (int qf = 0; qf < 2; qf++)
#pragma unroll
        for (int t5 = 0; t5 < 5; t5++) acc[qf][t5] = zero;

    // ones A-frag: row 0 of the l-tile accumulates l = sum_s P^T[s][q]
    bf16x8 ones;
#pragma unroll
    for (int e = 0; e < 8; e++) ones[e] = (l15 == 0) ? (__bf16)1.0f : (__bf16)0.0f;

    // staging: chunk c -> (row c>>3, swizzled col-chunk c&7)
    int c0 = tid, c1 = tid + 256;
    int s0 = c0 >> 3, d80 = ((c0 & 7) ^ (s0 & 7)) * 8;
    int s1 = c1 >> 3, d81 = ((c1 & 7) ^ (s1 & 7)) * 8;
    const __bf16* Kg0 = K + (rowb + s0) * CC + h * DH + d80;
    const __bf16* Kg1 = K + (rowb + s1) * CC + h * DH + d81;
    const __bf16* Vg0 = VT + (size_t)(h * DH + s0) * GM + rowb + d80;
    const __bf16* Vg1 = VT + (size_t)(h * DH + s1) * GM + rowb + d81;
    char* KsB = (char*)Ks; char* VsB = (char*)Vs;
    int wbase = (tid & ~63) * 16;

    // prologue: stage key-tile 0 into buffer 0
    GLD16(Kg0, KsB + wbase);
    GLD16(Kg1, KsB + 4096 + wbase);
    GLD16(Vg0, VsB + wbase);
    GLD16(Vg1, VsB + 4096 + wbase);

    int jmax = 2 * qt + 1;
    for (int j = 0; j <= jmax; j++) {
        __syncthreads();   // drains GLD(j) + all waves done reading other buf
        if (j < jmax) {    // prefetch tile j+1 into the other buffer
            int bo = ((j + 1) & 1) * 8192;
            GLD16(Kg0 + (size_t)(j + 1) * 64 * CC, KsB + bo + wbase);
            GLD16(Kg1 + (size_t)(j + 1) * 64 * CC, KsB + bo + 4096 + wbase);
            GLD16(Vg0 + (j + 1) * 64, VsB + bo + wbase);
            GLD16(Vg1 + (j + 1) * 64, VsB + bo + 4096 + wbase);
        }
        const __bf16* Kc = &Ks[j & 1][0];
        const __bf16* Vc = &Vs[j & 1][0];
        bool do0 = (j != jmax);          // strip 0 fully masked on the last k-tile

        // phase A: S^T = K.Q^T (pre-scaled)
        f32x4 s2[2][4];
#pragma unroll
        for (int st = 0; st < 4; st++) {
            bf16x8 k0f = *(const bf16x8*)(Kc + (st * 16 + l15) * 64 + ((q8 ^ x7) * 8));
            bf16x8 k1f = *(const bf16x8*)(Kc + (st * 16 + l15) * 64 + (((q8 + 4) ^ x7) * 8));
            f32x4 t1 = zero;
            t1 = MFMA16(k0f, qfr[1][0], t1);
            t1 = MFMA16(k1f, qfr[1][1], t1);
            s2[1][st] = t1;
            if (do0) {
                f32x4 t0 = zero;
                t0 = MFMA16(k0f, qfr[0][0], t0);
                t0 = MFMA16(k1f, qfr[0][1], t0);
                s2[0][st] = t0;
            }
        }

        // phase B: causal mask on the diagonal iter only (wave-uniform branch)
#pragma unroll
        for (int qf = 0; qf < 2; qf++) {
            if (qf == 0 && !do0) continue;
            if (j == 2 * qt + qf) {
#pragma unroll
                for (int st = 0; st < 4; st++) {
                    f32x4 t = s2[qf][st];
                    int sb = st * 16 + q8 * 4;
                    t.x = (sb + 0 > ql) ? -1e30f : t.x;
                    t.y = (sb + 1 > ql) ? -1e30f : t.y;
                    t.z = (sb + 2 > ql) ? -1e30f : t.z;
                    t.w = (sb + 3 > ql) ? -1e30f : t.w;
                    s2[qf][st] = t;
                }
            }
        }

        // phase C: P = exp2(s - M2); round-trip through per-wave LDS to A-layout
        bf16x8 bp[2][2];
#pragma unroll
        for (int qf = 0; qf < 2; qf++) {
            if (qf == 0 && !do0) continue;
#pragma unroll
            for (int st = 0; st < 4; st++) {
                bf16x4 pk;
                pk[0] = (__bf16)__builtin_amdgcn_exp2f(s2[qf][st].x - M2);
                pk[1] = (__bf16)__builtin_amdgcn_exp2f(s2[qf][st].y - M2);
                pk[2] = (__bf16)__builtin_amdgcn_exp2f(s2[qf][st].z - M2);
                pk[3] = (__bf16)__builtin_amdgcn_exp2f(s2[qf][st].w - M2);
                int swzc = (st * 2 + (q8 >> 1)) ^ x7;
                *(bf16x4*)(Ps[w] + l15 * 64 + swzc * 8 + (q8 & 1) * 4) = pk;
            }
            bp[qf][0] = *(const bf16x8*)(Ps[w] + l15 * 64 + ((q8 ^ x7) * 8));
            bp[qf][1] = *(const bf16x8*)(Ps[w] + l15 * 64 + (((q8 + 4) ^ x7) * 8));
        }

        // phase D: O^T += V^T P^T ; l-row via ones-MFMA
#pragma unroll
        for (int dt = 0; dt < 4; dt++) {
            bf16x8 v0 = *(const bf16x8*)(Vc + (dt * 16 + l15) * 64 + ((q8 ^ x7) * 8));
            bf16x8 v1 = *(const bf16x8*)(Vc + (dt * 16 + l15) * 64 + (((q8 + 4) ^ x7) * 8));
            acc[1][dt] = MFMA16(v0, bp[1][0], acc[1][dt]);
            acc[1][dt] = MFMA16(v1, bp[1][1], acc[1][dt]);
            if (do0) {
                acc[0][dt] = MFMA16(v0, bp[0][0], acc[0][dt]);
                acc[0][dt] = MFMA16(v1, bp[0][1], acc[0][dt]);
            }
        }
        acc[1][4] = MFMA16(ones, bp[1][0], acc[1][4]);
        acc[1][4] = MFMA16(ones, bp[1][1], acc[1][4]);
        if (do0) {
            acc[0][4] = MFMA16(ones, bp[0][0], acc[0][4]);
            acc[0][4] = MFMA16(ones, bp[0][1], acc[0][4]);
        }
    }

    // epilogue: O^T C-layout col=l15=q, row=q8*4+r=d; l in acc[qf][4].x at lane l15
#pragma unroll
    for (int qf = 0; qf < 2; qf++) {
        float lsum = __shfl(acc[qf][4].x, l15);
        float ri = 1.0f / lsum;
        int q = qt * 128 + qf * 64 + w * 16 + l15;
        __bf16* yp = Y + (rowb + q) * CC + h * DH + q8 * 4;
#pragma unroll
        for (int dt = 0; dt < 4; dt++) {
            bf16x4 o;
            o[0] = (__bf16)(acc[qf][dt].x * ri);
            o[1] = (__bf16)(acc[qf][dt].y * ri);
            o[2] = (__bf16)(acc[qf][dt].z * ri);
            o[3] = (__bf16)(acc[qf][dt].w * ri);
            *(bf16x4*)(yp + dt * 16) = o;
        }
    }
}

// ---------- launch ----------
extern "C" void kernel_launch(void* const* d_in, const int* in_sizes, int n_in,
                              void* d_out, int out_size, void* d_ws, size_t ws_size,
                              hipStream_t stream) {
    const float* x  = (const float*)d_in[0];
    const float* wq = (const float*)d_in[1];
    const float* wk = (const float*)d_in[2];
    const float* wv = (const float*)d_in[3];
    const float* wo = (const float*)d_in[4];
    float* out = (float*)d_out;

    char* ws = (char*)d_ws;
    __bf16* xb  = (__bf16*)ws;                              // [0,16M): x bf16 (A matrix)
    __bf16* wb  = (__bf16*)(ws + (size_t)16777216);         // [16M,24M): 4 weights bf16
    __bf16* qkv = (__bf16*)(ws + (size_t)25165824);         // [24M,72M): Q,K planes + VT in plane 2
    __bf16* yb  = (__bf16*)(ws + (size_t)75497472);         // [72M,88M): attn out bf16

    // fused conversion: x (4096 blocks) + 4 weight planes (4*512 blocks)
    cvt_all_kernel<<<dim3(4096 + 4 * 512), 256, 0, stream>>>(x, wq, wk, wv, wo, xb, wb);
    // fused QKV GEMM: M=8192, N=3072 (wq|wk|wv contiguous in wb), K=1024.
    // 768 blocks = 8 XCD x 96 = exactly 3 rounds; V plane written transposed.
    gemm8<<<dim3(768), 512, 0, stream>>>(xb, wb, qkv, nullptr);
    // grid: x = bh (64), y = balanced qt permutation (16); VT = qkv plane 2
    attn_kernel<<<dim3(BB * HH, 16), 256, 0, stream>>>(
        qkv, qkv + (size_t)GM * GN, qkv + (size_t)2 * GM * GN, yb);
    // output projection: 256 blocks = exactly 1 round, fp32 out
    gemm8<<<dim3(256), 512, 0, stream>>>(yb, wb + (size_t)3 * CC * CC, nullptr, out);
}